// Round 6
// baseline (249.567 us; speedup 1.0000x reference)
//
#include <hip/hip_runtime.h>
#include <hip/hip_bf16.h>

// EnTransformerBlock, MFMA v6: split-sender blocks (1024 x 512thr, 3/CU),
// wave=head softmax, kn-folded logits (no Lb), 50KB LDS, global merge kernel.
// N=512, V=8, F=128, H=8, FH=16, B=8. Dense all-pairs edges.
//
// ws layout (float offsets):
//   knB  @ 0        bf16[512][128]      (feat@Wk row-major)
//   vnT  @ 32768    bf16[128][512]      (feat@Wv transposed)
//   AW2  @ 65536    bf16[512][16][256]  (per r: rows 0-7: [A4 | 0.25*q masked],
//                                        rows 8-15: [Wg^T | 0])
//   W0T  @ 1114112  bf16[128][64]       (We0 transposed)
//   W1T  @ 1118208  bf16[128][128]      (We1 transposed)
//   PS   @ 1126400  [1024][1280]f32-equiv partial state per (r,half):
//         shorts 0..1023: bh bf16[8][128]; 1024..2047: sna bf16[8][128];
//         f32 1024..1215: av[8][24]; 1216..1223: m[8]; 1224..1231: d[8]

#define WS_KNB  0
#define WS_VNT  32768
#define WS_AW2  65536
#define WS_W0T  1114112
#define WS_W1T  1118208
#define WS_PS   1126400
#define PS_STRIDE 1280

typedef short bf16x8 __attribute__((ext_vector_type(8)));
typedef short short4v __attribute__((ext_vector_type(4)));
typedef float f32x4 __attribute__((ext_vector_type(4)));
typedef unsigned short ushort_t;

static __device__ __forceinline__ ushort_t f2b(float x) {
  __hip_bfloat16 h = __float2bfloat16(x);
  return reinterpret_cast<ushort_t&>(h);
}
static __device__ __forceinline__ float b2f(ushort_t u) {
  unsigned v = ((unsigned)u) << 16;
  return reinterpret_cast<float&>(v);
}
static __device__ __forceinline__ float fsilu(float x) {
  return x * __builtin_amdgcn_rcpf(1.f + __expf(-x));
}

static __device__ __forceinline__ bf16x8 radial_frag(
    float dx, float dy, float dz, float& ux, float& uy, float& uz)
{
  const float l2 = fmaf(dx,dx, fmaf(dy,dy, fmaf(dz,dz, 1e-20f)));
  const float inv = rsqrtf(l2);
  const float len = l2 * inv;
  ux = dx*inv; uy = dy*inv; uz = dz*inv;
  const float yy = 2.f - len*0.2f;
  const float env = (yy > 0.f) ? 1.9784655648f * __expf(-__builtin_amdgcn_rcpf(yy)) : 0.f;
  const float coef = 0.4472135955f * env * inv;
  const float arg = len * 0.31415926535f;
  const float s1v = __sinf(arg), c1v = __cosf(arg);
  const float twc = 2.f*c1v;
  float sp = 0.f, sc = s1v;
  bf16x8 ev;
#pragma unroll
  for (int bb = 0; bb < 8; ++bb) {
    ev[bb] = (short)f2b(coef*sc);
    const float nx = fmaf(twc, sc, -sp);
    sp = sc; sc = nx;
  }
  return ev;
}

__global__ __launch_bounds__(128) void k_nodeprep(
    const float* __restrict__ feat, const float* __restrict__ Wq,
    const float* __restrict__ Wk, const float* __restrict__ Wv,
    const float* __restrict__ Wek, const float* __restrict__ Wg,
    float* __restrict__ ws)
{
  const int r = blockIdx.x, j = threadIdx.x;
  __shared__ float fr[128];
  __shared__ float qL[128];
  fr[j] = feat[r*128 + j];
  __syncthreads();
  float aq = 0.f, ak = 0.f, av = 0.f;
#pragma unroll 4
  for (int i = 0; i < 128; ++i) {
    const float f = fr[i];
    aq = fmaf(f, Wq[i*128 + j], aq);
    ak = fmaf(f, Wk[i*128 + j], ak);
    av = fmaf(f, Wv[i*128 + j], av);
  }
  ushort_t* knB = (ushort_t*)(ws + WS_KNB);
  ushort_t* vnT = (ushort_t*)(ws + WS_VNT);
  knB[r*128 + j] = f2b(ak);
  vnT[j*512 + r] = f2b(av);
  qL[j] = aq;
  __syncthreads();
  ushort_t* AW = (ushort_t*)(ws + WS_AW2) + r*4096;
  const float* wr = Wek + j*128;
  const int jh = j >> 4;
#pragma unroll
  for (int h = 0; h < 8; ++h) {
    float acc = 0.f;
#pragma unroll
    for (int f = 0; f < 16; ++f)
      acc = fmaf(wr[16*h + f], qL[16*h + f], acc);
    AW[h*256 + j] = f2b(acc * 0.25f);
    AW[h*256 + 128 + j] = (h == jh) ? f2b(0.25f * aq) : (ushort_t)0;
  }
#pragma unroll
  for (int v = 0; v < 8; ++v) {
    AW[(8 + v)*256 + j] = f2b(Wg[j*8 + v]);
    AW[(8 + v)*256 + 128 + j] = 0;
  }
}

__global__ __launch_bounds__(256) void k_wprep(
    const float* __restrict__ We0, const float* __restrict__ We1,
    float* __restrict__ ws)
{
  const int i = blockIdx.x*256 + threadIdx.x;
  ushort_t* W0T = (ushort_t*)(ws + WS_W0T);
  ushort_t* W1T = (ushort_t*)(ws + WS_W1T);
  if (i < 8192) {
    const int n = i >> 6, k = i & 63;
    W0T[n*64 + k] = f2b(We0[k*128 + n]);
  } else if (i < 24576) {
    const int t = i - 8192, n = t >> 7, k = t & 127;
    W1T[n*128 + k] = f2b(We1[k*128 + n]);
  }
}

// LDS (bytes): Es@0 [64][64]bf16 8192 | H1@8192 [64][128]bf16 16384 |
//   H2t@24576 [128][64]bf16 16384 | uCt@40960 [32][64]bf16 4096 |
//   lgT@45056 [16][64]f32 4096 | Pb@49152 [16][64]bf16 2048 | rscL@51200 f32[8]
#define MFMA(a,b,c) __builtin_amdgcn_mfma_f32_16x16x32_bf16((a),(b),(c),0,0,0)

__global__ __launch_bounds__(512, 6) void k_edge6(
    const float* __restrict__ pos,
    const float* __restrict__ be0, const float* __restrict__ be1,
    float* __restrict__ ws)
{
  __shared__ __align__(16) char Lds[51232];
  ushort_t* Es  = (ushort_t*)(Lds);
  ushort_t* H1  = (ushort_t*)(Lds + 8192);
  ushort_t* H2t = (ushort_t*)(Lds + 24576);
  ushort_t* uCt = (ushort_t*)(Lds + 40960);
  float*    lgT = (float*)(Lds + 45056);
  ushort_t* Pb  = (ushort_t*)(Lds + 49152);
  float*    rscL= (float*)(Lds + 51200);

  const int tid = threadIdx.x;
  const int nw = tid >> 6, l = tid & 63;
  const int c = l & 15, g = l >> 4;
  const int b = blockIdx.x;
  const int r = b >> 1, half = b & 1;
  const int base = half * 256;

  const ushort_t* knB = (const ushort_t*)(ws + WS_KNB);
  const ushort_t* vnT = (const ushort_t*)(ws + WS_VNT);
  const ushort_t* AW2 = (const ushort_t*)(ws + WS_AW2) + r*4096;
  const ushort_t* W0T = (const ushort_t*)(ws + WS_W0T);
  const ushort_t* W1T = (const ushort_t*)(ws + WS_W1T);

  const int ncol = nw*16 + c;
  const float be0v = be0[ncol], be1v = be1[ncol];
  const bf16x8 w0f0 = *(const bf16x8*)(W0T + ncol*64 + g*8);
  const bf16x8 w0f1 = *(const bf16x8*)(W0T + ncol*64 + 32 + g*8);

  // LG role: m-block m_lg, k-half kh (0: H2 part, 1: kn part)
  const int m_lg = nw & 3, kh = nw >> 2;
  bf16x8 awf[4];
#pragma unroll
  for (int kb = 0; kb < 4; ++kb)
    awf[kb] = *(const bf16x8*)(AW2 + c*256 + kh*128 + kb*32 + g*8);

  // geometry identity: wave nw <-> vector v = nw; lane l <-> sender slot l
  const float prx = pos[r*24 + nw*3 + 0];
  const float pry = pos[r*24 + nw*3 + 1];
  const float prz = pos[r*24 + nw*3 + 2];

  // prologue: zero lgT + uCt pad rows; geometry tile 0
  lgT[tid] = 0.f;
  lgT[512 + tid] = 0.f;
  uCt[1536 + tid] = 0;
  float ux, uy, uz;
  {
    const int sg = base + l;
    const bf16x8 ev = radial_frag(pos[sg*24 + nw*3 + 0] - prx,
                                  pos[sg*24 + nw*3 + 1] - pry,
                                  pos[sg*24 + nw*3 + 2] - prz, ux, uy, uz);
    *(bf16x8*)(Es + l*64 + ((nw ^ (l&7))<<3)) = ev;
  }

  f32x4 bh = {0,0,0,0}, sna = {0,0,0,0}, av = {0,0,0,0};
  float mrun = -1e30f, drun = 0.f;
  __syncthreads();

  for (int tile = 0; tile < 4; ++tile) {
    const int gbase = base + tile*64;

    // prefetch (consumed in s1)
    bf16x8 w1f[4];
#pragma unroll
    for (int kb = 0; kb < 4; ++kb)
      w1f[kb] = *(const bf16x8*)(W1T + ncol*128 + kb*32 + g*8);
    float npx = 0.f, npy = 0.f, npz = 0.f;
    if (tile < 3) {
      const int sg = gbase + 64 + l;
      npx = pos[sg*24 + nw*3 + 0];
      npy = pos[sg*24 + nw*3 + 1];
      npz = pos[sg*24 + nw*3 + 2];
    }

    // ---- s0: L0 (Es @ We0 -> H1) ----
#pragma unroll
    for (int m = 0; m < 4; ++m) {
      const int ra = m*16 + c;
      const bf16x8 e0 = *(const bf16x8*)(Es + ra*64 + (((g  ) ^ (ra&7))<<3));
      const bf16x8 e1 = *(const bf16x8*)(Es + ra*64 + (((4+g) ^ (ra&7))<<3));
      f32x4 acc = {0,0,0,0};
      acc = MFMA(e0, w0f0, acc);
      acc = MFMA(e1, w0f1, acc);
#pragma unroll
      for (int i = 0; i < 4; ++i) {
        const int row = m*16 + g*4 + i;
        H1[row*128 + (((ncol>>3) ^ (row&15))<<3) + (c&7)] =
            f2b(fsilu(acc[i] + be0v));
      }
    }
    __syncthreads();  // B: H1 ready

    // ---- s1: L1 (H1 @ We1 -> H2t) + geometry(t+1) ----
#pragma unroll
    for (int m = 0; m < 4; ++m) {
      const int ra = m*16 + c;
      f32x4 acc = {0,0,0,0};
#pragma unroll
      for (int kb = 0; kb < 4; ++kb) {
        const bf16x8 af = *(const bf16x8*)(H1 + ra*128 + (((kb*4+g) ^ (ra&15))<<3));
        acc = MFMA(af, w1f[kb], acc);
      }
      short4v pk;
#pragma unroll
      for (int i = 0; i < 4; ++i)
        pk[i] = (short)f2b(fsilu(acc[i] + be1v));
      *(short4v*)(H2t + ncol*64 + (((m*2 + (g>>1)) ^ (ncol&7))<<3) + ((g&1)<<2)) = pk;
    }
    float nux = 0.f, nuy = 0.f, nuz = 0.f;
    if (tile < 3) {
      const bf16x8 ev = radial_frag(npx - prx, npy - pry, npz - prz, nux, nuy, nuz);
      *(bf16x8*)(Es + l*64 + ((nw ^ (l&7))<<3)) = ev;
    }
    // kn fragments for LG (L2-hot; overlapped with barrier)
    bf16x8 knf[4];
    if (kh == 1) {
#pragma unroll
      for (int kb = 0; kb < 4; ++kb)
        knf[kb] = *(const bf16x8*)(knB + (gbase + m_lg*16 + c)*128 + kb*32 + g*8);
    }
    __syncthreads();  // C: H2t ready

    // ---- s2: LG partial -> lgT (atomic add, 2 contributors/loc) ----
    {
      f32x4 lg = {0,0,0,0};
      if (kh == 0) {
        const int sL = m_lg*16 + c;
        const int swL = (((sL>>3)<<3) ^ 0);  // sL>>3 base
#pragma unroll
        for (int kb = 0; kb < 4; ++kb) {
          bf16x8 bb;
#pragma unroll
          for (int j = 0; j < 8; ++j) {
            const int col = kb*32 + g*8 + j;
            bb[j] = (short)H2t[col*64 + (((sL>>3) ^ (col&7))<<3) + (sL&7)];
          }
          lg = MFMA(awf[kb], bb, lg);
        }
        (void)swL;
      } else {
#pragma unroll
        for (int kb = 0; kb < 4; ++kb)
          lg = MFMA(awf[kb], knf[kb], lg);
      }
#pragma unroll
      for (int i = 0; i < 4; ++i)
        atomicAdd(&lgT[(4*g + i)*64 + m_lg*16 + c], lg[i]);
    }
    __syncthreads();  // S1: lgT complete

    // ---- s3: softmax (wave = head) + uCt write + vn prefetch ----
    const bf16x8 vnf0 = *(const bf16x8*)(vnT + ncol*512 + gbase + g*8);
    const bf16x8 vnf1 = *(const bf16x8*)(vnT + ncol*512 + gbase + 32 + g*8);
    {
      const int h = nw;
      float lgv  = lgT[h*64 + l];
      const float gate = lgT[(8+h)*64 + l];
      if (gbase + l == r) lgv = -1e30f;
      float t = lgv;
      t = fmaxf(t, __shfl_xor(t, 1));
      t = fmaxf(t, __shfl_xor(t, 2));
      t = fmaxf(t, __shfl_xor(t, 4));
      t = fmaxf(t, __shfl_xor(t, 8));
      t = fmaxf(t, __shfl_xor(t, 16));
      t = fmaxf(t, __shfl_xor(t, 32));
      const float mnew = fmaxf(mrun, t);
      const float rsc = __expf(mrun - mnew);
      mrun = mnew;
      const float val = __expf(lgv - mnew);
      float wsm = val;
      wsm += __shfl_xor(wsm, 1);
      wsm += __shfl_xor(wsm, 2);
      wsm += __shfl_xor(wsm, 4);
      wsm += __shfl_xor(wsm, 8);
      wsm += __shfl_xor(wsm, 16);
      wsm += __shfl_xor(wsm, 32);
      drun = drun*rsc + wsm;
      Pb[h*64 + (((l>>3) ^ (h&7))<<3) + (l&7)] = f2b(val);
      Pb[(8+h)*64 + (((l>>3) ^ ((8+h)&7))<<3) + (l&7)] = f2b(val * gate);
      lgT[h*64 + l] = 0.f;
      lgT[(8+h)*64 + l] = 0.f;
      if (l == 0) rscL[h] = rsc;
      // uCt for THIS tile (u regs computed one stage earlier)
      const int v3 = nw*3;
      uCt[(v3+0)*64 + (((l>>3) ^ ((v3+0)&7))<<3) + (l&7)] = f2b(ux);
      uCt[(v3+1)*64 + (((l>>3) ^ ((v3+1)&7))<<3) + (l&7)] = f2b(uy);
      uCt[(v3+2)*64 + (((l>>3) ^ ((v3+2)&7))<<3) + (l&7)] = f2b(uz);
    }
    __syncthreads();  // S: Pb/rscL/uCt ready

    // ---- s4: rescale + P-MFMAs ----
    {
      float rs[4];
#pragma unroll
      for (int i = 0; i < 4; ++i) rs[i] = rscL[(4*g + i) & 7];
#pragma unroll
      for (int i = 0; i < 4; ++i) { bh[i] *= rs[i]; sna[i] *= rs[i]; av[i] *= rs[i]; }
      const bf16x8 pa0 = *(const bf16x8*)(Pb + c*64 + (((g  ) ^ (c&7))<<3));
      const bf16x8 pa1 = *(const bf16x8*)(Pb + c*64 + (((4+g) ^ (c&7))<<3));
      bh = MFMA(pa0, *(const bf16x8*)(H2t + ncol*64 + (((g  ) ^ (ncol&7))<<3)), bh);
      bh = MFMA(pa1, *(const bf16x8*)(H2t + ncol*64 + (((4+g) ^ (ncol&7))<<3)), bh);
      sna = MFMA(pa0, vnf0, sna);
      sna = MFMA(pa1, vnf1, sna);
      if (nw == 4 || nw == 5) {
        const int vc = (nw - 4)*16 + c;
        av = MFMA(pa0, *(const bf16x8*)(uCt + vc*64 + (((g  ) ^ (vc&7))<<3)), av);
        av = MFMA(pa1, *(const bf16x8*)(uCt + vc*64 + (((4+g) ^ (vc&7))<<3)), av);
      }
    }
    if (tile < 3) { ux = nux; uy = nuy; uz = nuz; }
  }

  // ---- write partial state ----
  float* PSf = ws + WS_PS + b*PS_STRIDE;
  ushort_t* PSs = (ushort_t*)PSf;
  if (g < 2) {
#pragma unroll
    for (int i = 0; i < 4; ++i) {
      PSs[(4*g + i)*128 + ncol] = f2b(bh[i]);
      PSs[1024 + (4*g + i)*128 + ncol] = f2b(sna[i]);
    }
  }
  if ((nw == 4 || nw == 5) && g >= 2) {
    const int vc = (nw - 4)*16 + c;
    if (vc < 24) {
#pragma unroll
      for (int i = 0; i < 4; ++i)
        PSf[1024 + (4*(g-2) + i)*24 + vc] = av[i];
    }
  }
  if (l == 0) { PSf[1216 + nw] = mrun; PSf[1224 + nw] = drun; }
}

__global__ __launch_bounds__(128) void k_merge(
    const float* __restrict__ pos, const float* __restrict__ feat,
    const float* __restrict__ Wev,
    const float* __restrict__ Wo0, const float* __restrict__ bo0,
    const float* __restrict__ Wo1, const float* __restrict__ bo1,
    const float* __restrict__ Wo2, const float* __restrict__ bo2,
    const float* __restrict__ ws, float* __restrict__ out)
{
  const int r = blockIdx.x, j = threadIdx.x;
  __shared__ float S1s[8], S2s[8], Dh[8];
  __shared__ float BhC[1024];
  __shared__ float asB[128], o1[128], o2[128];
  const float* P1f = ws + WS_PS + (2*r)*PS_STRIDE;
  const float* P2f = P1f + PS_STRIDE;
  const ushort_t* P1s = (const ushort_t*)P1f;
  const ushort_t* P2s = (const ushort_t*)P2f;
  if (j < 8) {
    const float m1 = P1f[1216 + j], m2 = P2f[1216 + j];
    const float M = fmaxf(m1, m2);
    const float s1 = __expf(m1 - M), s2 = __expf(m2 - M);
    S1s[j] = s1; S2s[j] = s2;
    Dh[j] = s1*P1f[1224 + j] + s2*P2f[1224 + j];
  }
  __syncthreads();
#pragma unroll
  for (int h = 0; h < 8; ++h)
    BhC[h*128 + j] = S1s[h]*b2f(P1s[h*128 + j]) + S2s[h]*b2f(P2s[h*128 + j]);
  const int hh = j >> 4;
  const float snj = S1s[hh]*b2f(P1s[1024 + hh*128 + j])
                  + S2s[hh]*b2f(P2s[1024 + hh*128 + j]);
  if (j < 24) {
    const int v = j / 3;
    const float avc = S1s[v]*P1f[1024 + v*24 + j] + S2s[v]*P2f[1024 + v*24 + j];
    out[r*24 + j] = pos[r*24 + j]
        + 1.7320508076f * avc * __builtin_amdgcn_rcpf(Dh[v]);
  }
  __syncthreads();
  {
    float ev = 0.f;
#pragma unroll 4
    for (int m = 0; m < 128; ++m)
      ev = fmaf(BhC[hh*128 + m], Wev[m*128 + j], ev);
    asB[j] = (snj + ev) * __builtin_amdgcn_rcpf(Dh[hh]);
  }
  __syncthreads();
  {
    float acc = bo0[j];
#pragma unroll 4
    for (int i = 0; i < 128; ++i) acc = fmaf(asB[i], Wo0[i*128 + j], acc);
    o1[j] = fsilu(acc);
  }
  __syncthreads();
  {
    float acc = bo1[j];
#pragma unroll 4
    for (int i = 0; i < 128; ++i) acc = fmaf(o1[i], Wo1[i*128 + j], acc);
    o2[j] = fsilu(acc);
  }
  __syncthreads();
  {
    float acc = bo2[j];
#pragma unroll 4
    for (int i = 0; i < 128; ++i) acc = fmaf(o2[i], Wo2[i*128 + j], acc);
    out[12288 + r*128 + j] = feat[r*128 + j] + acc;
  }
}

extern "C" void kernel_launch(void* const* d_in, const int* in_sizes, int n_in,
                              void* d_out, int out_size, void* d_ws, size_t ws_size,
                              hipStream_t stream)
{
  const float* pos  = (const float*)d_in[0];
  const float* feat = (const float*)d_in[1];
  const float* We0  = (const float*)d_in[2];
  const float* be0  = (const float*)d_in[3];
  const float* We1  = (const float*)d_in[4];
  const float* be1  = (const float*)d_in[5];
  const float* Wq   = (const float*)d_in[6];
  const float* Wk   = (const float*)d_in[7];
  const float* Wek  = (const float*)d_in[8];
  const float* Wv   = (const float*)d_in[9];
  const float* Wev  = (const float*)d_in[10];
  const float* Wg   = (const float*)d_in[11];
  const float* Wo0  = (const float*)d_in[12];
  const float* bo0  = (const float*)d_in[13];
  const float* Wo1  = (const float*)d_in[14];
  const float* bo1  = (const float*)d_in[15];
  const float* Wo2  = (const float*)d_in[16];
  const float* bo2  = (const float*)d_in[17];
  float* ws  = (float*)d_ws;
  float* out = (float*)d_out;

  hipLaunchKernelGGL(k_nodeprep, dim3(512), dim3(128), 0, stream,
                     feat, Wq, Wk, Wv, Wek, Wg, ws);
  hipLaunchKernelGGL(k_wprep, dim3(96), dim3(256), 0, stream, We0, We1, ws);
  hipLaunchKernelGGL(k_edge6, dim3(1024), dim3(512), 0, stream,
                     pos, be0, be1, ws);
  hipLaunchKernelGGL(k_merge, dim3(512), dim3(128), 0, stream,
                     pos, feat, Wev, Wo0, bo0, Wo1, bo1, Wo2, bo2, ws, out);
}

// Round 7
// 195.349 us; speedup vs baseline: 1.2775x; 1.2775x over previous
//
#include <hip/hip_runtime.h>
#include <hip/hip_bf16.h>

// EnTransformerBlock, MFMA v7: 3 blocks/CU (47KB LDS, lean regs), split-sender
// grid 1024, wave=head softmax, Lb table (bf16), VALU equivariant path.
// N=512, V=8, F=128, H=8, FH=16, B=8. Dense all-pairs edges.
//
// ws layout (float offsets):
//   kn   @ 0        f32 [512][128]
//   qn   @ 65536    f32 [512][128]
//   LbB  @ 131072   bf16[512][512][8]   (q.k per head, /4)        -> 1179648
//   vnT  @ 1179648  bf16[128][512]      (feat@Wv transposed)      -> 1212416
//   A4T  @ 1212416  bf16[512][8][128]   (Wek folded with q, /4)   -> 1474560
//   WgT  @ 1474560  bf16[8][128]        (Wg transposed)           -> 1475072
//   W0T  @ 1475072  bf16[128][64]       (We0 transposed)          -> 1479168
//   W1T  @ 1479168  bf16[128][128]      (We1 transposed)          -> 1487360
//   PS   @ 1487360  [1024][1072]f: shorts 0..1023 bh[8][128],
//        1024..2047 sna[8][128]; f32 1024..1047 av[8][3],
//        1048..1055 m[8], 1056..1063 d[8]                          -> 2585088

#define WS_KN   0
#define WS_QN   65536
#define WS_LBB  131072
#define WS_VNT  1179648
#define WS_A4T  1212416
#define WS_WGT  1474560
#define WS_W0T  1475072
#define WS_W1T  1479168
#define WS_PS   1487360
#define PS_STRIDE 1072

typedef short bf16x8 __attribute__((ext_vector_type(8)));
typedef short short4v __attribute__((ext_vector_type(4)));
typedef float f32x4 __attribute__((ext_vector_type(4)));
typedef unsigned short ushort_t;

static __device__ __forceinline__ ushort_t f2b(float x) {
  __hip_bfloat16 h = __float2bfloat16(x);
  return reinterpret_cast<ushort_t&>(h);
}
static __device__ __forceinline__ float b2f(ushort_t u) {
  unsigned v = ((unsigned)u) << 16;
  return reinterpret_cast<float&>(v);
}
static __device__ __forceinline__ float fsilu(float x) {
  return x * __builtin_amdgcn_rcpf(1.f + __expf(-x));
}

static __device__ __forceinline__ bf16x8 radial_frag(
    float dx, float dy, float dz, float& ux, float& uy, float& uz)
{
  const float l2 = fmaf(dx,dx, fmaf(dy,dy, fmaf(dz,dz, 1e-20f)));
  const float inv = rsqrtf(l2);
  const float len = l2 * inv;
  ux = dx*inv; uy = dy*inv; uz = dz*inv;
  const float yy = 2.f - len*0.2f;
  const float env = (yy > 0.f) ? 1.9784655648f * __expf(-__builtin_amdgcn_rcpf(yy)) : 0.f;
  const float coef = 0.4472135955f * env * inv;
  const float arg = len * 0.31415926535f;
  const float s1v = __sinf(arg), c1v = __cosf(arg);
  const float twc = 2.f*c1v;
  float sp = 0.f, sc = s1v;
  bf16x8 ev;
#pragma unroll
  for (int bb = 0; bb < 8; ++bb) {
    ev[bb] = (short)f2b(coef*sc);
    const float nx = fmaf(twc, sc, -sp);
    sp = sc; sc = nx;
  }
  return ev;
}

__global__ __launch_bounds__(128) void k_nodeprep(
    const float* __restrict__ feat, const float* __restrict__ Wq,
    const float* __restrict__ Wk, const float* __restrict__ Wv,
    const float* __restrict__ Wek, const float* __restrict__ Wg,
    float* __restrict__ ws)
{
  const int r = blockIdx.x, j = threadIdx.x;
  __shared__ float fr[128];
  __shared__ float qL[128];
  fr[j] = feat[r*128 + j];
  __syncthreads();
  float aq = 0.f, ak = 0.f, av = 0.f;
#pragma unroll 4
  for (int i = 0; i < 128; ++i) {
    const float f = fr[i];
    aq = fmaf(f, Wq[i*128 + j], aq);
    ak = fmaf(f, Wk[i*128 + j], ak);
    av = fmaf(f, Wv[i*128 + j], av);
  }
  ws[WS_QN + r*128 + j] = aq;
  ws[WS_KN + r*128 + j] = ak;
  ushort_t* vnT = (ushort_t*)(ws + WS_VNT);
  vnT[j*512 + r] = f2b(av);
  qL[j] = aq;
  __syncthreads();
  ushort_t* A4 = (ushort_t*)(ws + WS_A4T) + r*1024;
  const float* wr = Wek + j*128;
#pragma unroll
  for (int h = 0; h < 8; ++h) {
    float acc = 0.f;
#pragma unroll
    for (int f = 0; f < 16; ++f)
      acc = fmaf(wr[16*h + f], qL[16*h + f], acc);
    A4[h*128 + j] = f2b(acc * 0.25f);
  }
  if (r == 0) {
    ushort_t* WgT = (ushort_t*)(ws + WS_WGT);
#pragma unroll
    for (int v = 0; v < 8; ++v)
      WgT[v*128 + j] = f2b(Wg[j*8 + v]);
  }
}

__global__ __launch_bounds__(512) void k_lbase(float* __restrict__ ws)
{
  const int r = blockIdx.x, s = threadIdx.x;
  __shared__ float qL[128];
  if (s < 128) qL[s] = ws[WS_QN + r*128 + s];
  __syncthreads();
  const float* knr = ws + WS_KN + s*128;
  ushort_t* Lb = (ushort_t*)(ws + WS_LBB) + (r*512 + s)*8;
#pragma unroll
  for (int h = 0; h < 8; ++h) {
    float acc = 0.f;
#pragma unroll
    for (int f = 0; f < 16; ++f)
      acc = fmaf(knr[16*h + f], qL[16*h + f], acc);
    Lb[h] = f2b(acc * 0.25f);
  }
}

__global__ __launch_bounds__(256) void k_wprep(
    const float* __restrict__ We0, const float* __restrict__ We1,
    float* __restrict__ ws)
{
  const int i = blockIdx.x*256 + threadIdx.x;
  ushort_t* W0T = (ushort_t*)(ws + WS_W0T);
  ushort_t* W1T = (ushort_t*)(ws + WS_W1T);
  if (i < 8192) {
    const int n = i >> 6, k = i & 63;
    W0T[n*64 + k] = f2b(We0[k*128 + n]);
  } else if (i < 24576) {
    const int t = i - 8192, n = t >> 7, k = t & 127;
    W1T[n*128 + k] = f2b(We1[k*128 + n]);
  }
}

// LDS (bytes): Es@0 [64][64]bf16 8192 | H1/H2r@8192 [64][128]bf16 16384 |
//   H2t@24576 [128][64]bf16 16384 | lgT@40960 f32[16][65] 4160 |
//   Pb@45120 bf16[16][64] 2048 | rscL@47168 f32[8] 32   (total 47200)
#define MFMA(a,b,c) __builtin_amdgcn_mfma_f32_16x16x32_bf16((a),(b),(c),0,0,0)

__global__ __launch_bounds__(512, 6) void k_edge7(
    const float* __restrict__ pos,
    const float* __restrict__ be0, const float* __restrict__ be1,
    float* __restrict__ ws)
{
  __shared__ __align__(16) char Lds[47232];
  ushort_t* Es  = (ushort_t*)(Lds);
  ushort_t* H1  = (ushort_t*)(Lds + 8192);
  ushort_t* H2t = (ushort_t*)(Lds + 24576);
  float*    lgT = (float*)(Lds + 40960);
  ushort_t* Pb  = (ushort_t*)(Lds + 45120);
  float*    rscL= (float*)(Lds + 47168);

  const int tid = threadIdx.x;
  const int nw = tid >> 6, l = tid & 63;
  const int c = l & 15, g = l >> 4;
  const int b = blockIdx.x;
  const int r = b >> 1, half = b & 1;
  const int base = half * 256;

  const ushort_t* vnT = (const ushort_t*)(ws + WS_VNT);
  const ushort_t* A4G = (const ushort_t*)(ws + WS_A4T) + r*1024;
  const ushort_t* WgG = (const ushort_t*)(ws + WS_WGT);
  const ushort_t* W0T = (const ushort_t*)(ws + WS_W0T);
  const ushort_t* W1T = (const ushort_t*)(ws + WS_W1T);
  const ushort_t* LbG = (const ushort_t*)(ws + WS_LBB) + r*4096;

  const int ncol = nw*16 + c;
  const float be0v = be0[ncol], be1v = be1[ncol];
  const bf16x8 w0f0 = *(const bf16x8*)(W0T + ncol*64 + g*8);
  const bf16x8 w0f1 = *(const bf16x8*)(W0T + ncol*64 + 32 + g*8);

  // geometry identity: wave nw <-> vector v=nw, lane l <-> sender slot l
  const float prx = pos[r*24 + nw*3 + 0];
  const float pry = pos[r*24 + nw*3 + 1];
  const float prz = pos[r*24 + nw*3 + 2];

  f32x4 bh = {0,0,0,0}, sna = {0,0,0,0};
  float avx = 0.f, avy = 0.f, avz = 0.f;
  float mrun = -1e30f, drun = 0.f;
  float ux, uy, uz;

  // prologue: geometry tile 0
  {
    const int sg = base + l;
    const bf16x8 ev = radial_frag(pos[sg*24 + nw*3 + 0] - prx,
                                  pos[sg*24 + nw*3 + 1] - pry,
                                  pos[sg*24 + nw*3 + 2] - prz, ux, uy, uz);
    *(bf16x8*)(Es + l*64 + ((nw ^ (l&7))<<3)) = ev;
  }
  __syncthreads();

  for (int tile = 0; tile < 4; ++tile) {
    const int gbase = base + tile*64;

    // early global prefetches (consumed stages later)
    float npx = 0.f, npy = 0.f, npz = 0.f;
    if (tile < 3) {
      const int sg = gbase + 64 + l;
      npx = pos[sg*24 + nw*3 + 0];
      npy = pos[sg*24 + nw*3 + 1];
      npz = pos[sg*24 + nw*3 + 2];
    }
    const ushort_t lbp = LbG[(gbase + l)*8 + nw];

    // ---- s0: L0 (Es @ We0 -> H1) ----
#pragma unroll
    for (int m = 0; m < 4; ++m) {
      const int ra = m*16 + c;
      const bf16x8 e0 = *(const bf16x8*)(Es + ra*64 + (((g  ) ^ (ra&7))<<3));
      const bf16x8 e1 = *(const bf16x8*)(Es + ra*64 + (((4+g) ^ (ra&7))<<3));
      f32x4 acc = {0,0,0,0};
      acc = MFMA(e0, w0f0, acc);
      acc = MFMA(e1, w0f1, acc);
#pragma unroll
      for (int i = 0; i < 4; ++i) {
        const int row = m*16 + g*4 + i;
        H1[row*128 + (((ncol>>3) ^ (row&15))<<3) + (c&7)] =
            f2b(fsilu(acc[i] + be0v));
      }
    }
    __syncthreads();  // B: H1 ready

    // ---- s1a: L1 accumulate (reads H1) + geometry(t+1) ----
    f32x4 a1[4];
#pragma unroll
    for (int m = 0; m < 4; ++m) {
      const int ra = m*16 + c;
      f32x4 acc = {0,0,0,0};
#pragma unroll
      for (int kb = 0; kb < 4; ++kb) {
        const bf16x8 af = *(const bf16x8*)(H1 + ra*128 + (((kb*4+g) ^ (ra&15))<<3));
        const bf16x8 wf = *(const bf16x8*)(W1T + ncol*128 + kb*32 + g*8);
        acc = MFMA(af, wf, acc);
      }
      a1[m] = acc;
    }
    float nux = 0.f, nuy = 0.f, nuz = 0.f;
    if (tile < 3) {
      const bf16x8 ev = radial_frag(npx - prx, npy - pry, npz - prz, nux, nuy, nuz);
      *(bf16x8*)(Es + l*64 + ((nw ^ (l&7))<<3)) = ev;
    }
    __syncthreads();  // C1: H1 fully consumed; Es(t+1) staged

    // ---- s1b: silu -> H2r (aliases H1) + H2t ----
#pragma unroll
    for (int m = 0; m < 4; ++m) {
      short4v pk;
#pragma unroll
      for (int i = 0; i < 4; ++i) {
        const int row = m*16 + g*4 + i;
        const ushort_t bv = f2b(fsilu(a1[m][i] + be1v));
        H1[row*128 + (((ncol>>3) ^ (row&15))<<3) + (c&7)] = bv;
        pk[i] = (short)bv;
      }
      *(short4v*)(H2t + ncol*64 + (((m*2 + (g>>1)) ^ (ncol&7))<<3) + ((g&1)<<2)) = pk;
    }
    __syncthreads();  // C2: H2r/H2t ready

    // ---- s2: LG (waves 0-3): lg[sender][ch] -> lgT[ch][sender] ----
    if (nw < 4) {
      const int ra = nw*16 + c;
      const ushort_t* ab = (c < 8) ? (A4G + c*128) : (WgG + (c-8)*128);
      f32x4 lg = {0,0,0,0};
#pragma unroll
      for (int kb = 0; kb < 4; ++kb) {
        const bf16x8 af = *(const bf16x8*)(H1 + ra*128 + (((kb*4+g) ^ (ra&15))<<3));
        const bf16x8 aw = *(const bf16x8*)(ab + kb*32 + g*8);
        lg = MFMA(af, aw, lg);
      }
#pragma unroll
      for (int i = 0; i < 4; ++i)
        lgT[c*65 + nw*16 + g*4 + i] = lg[i];
    }
    __syncthreads();  // S1: lgT ready

    // ---- s3: softmax (wave = head h = nw) + equivariant VALU accum ----
    const bf16x8 vnf0 = *(const bf16x8*)(vnT + ncol*512 + gbase + g*8);
    const bf16x8 vnf1 = *(const bf16x8*)(vnT + ncol*512 + gbase + 32 + g*8);
    {
      const int h = nw;
      float lgv = lgT[h*65 + l] + b2f(lbp);
      const float gate = lgT[(8+h)*65 + l];
      if (gbase + l == r) lgv = -1e30f;
      float t = lgv;
      t = fmaxf(t, __shfl_xor(t, 1));
      t = fmaxf(t, __shfl_xor(t, 2));
      t = fmaxf(t, __shfl_xor(t, 4));
      t = fmaxf(t, __shfl_xor(t, 8));
      t = fmaxf(t, __shfl_xor(t, 16));
      t = fmaxf(t, __shfl_xor(t, 32));
      const float mnew = fmaxf(mrun, t);
      const float rsc = __expf(mrun - mnew);
      mrun = mnew;
      const float val = __expf(lgv - mnew);
      float wsm = val;
      wsm += __shfl_xor(wsm, 1);
      wsm += __shfl_xor(wsm, 2);
      wsm += __shfl_xor(wsm, 4);
      wsm += __shfl_xor(wsm, 8);
      wsm += __shfl_xor(wsm, 16);
      wsm += __shfl_xor(wsm, 32);
      drun = drun*rsc + wsm;
      const float ga = val * gate;
      Pb[h*64 + (((l>>3) ^ h)<<3) + (l&7)] = f2b(val);
      Pb[(8+h)*64 + (((l>>3) ^ h)<<3) + (l&7)] = f2b(ga);
      if (l == 0) rscL[h] = rsc;
      avx = avx*rsc + ga*ux;
      avy = avy*rsc + ga*uy;
      avz = avz*rsc + ga*uz;
    }
    __syncthreads();  // S2: Pb/rscL ready

    // ---- s4: rescale + P-MFMAs ----
    {
      float rs[4];
#pragma unroll
      for (int i = 0; i < 4; ++i) rs[i] = rscL[(4*g + i) & 7];
#pragma unroll
      for (int i = 0; i < 4; ++i) { bh[i] *= rs[i]; sna[i] *= rs[i]; }
      const bf16x8 pa0 = *(const bf16x8*)(Pb + c*64 + (((g  ) ^ (c&7))<<3));
      const bf16x8 pa1 = *(const bf16x8*)(Pb + c*64 + (((4+g) ^ (c&7))<<3));
      bh = MFMA(pa0, *(const bf16x8*)(H2t + ncol*64 + (((g  ) ^ (ncol&7))<<3)), bh);
      bh = MFMA(pa1, *(const bf16x8*)(H2t + ncol*64 + (((4+g) ^ (ncol&7))<<3)), bh);
      sna = MFMA(pa0, vnf0, sna);
      sna = MFMA(pa1, vnf1, sna);
    }
    if (tile < 3) { ux = nux; uy = nuy; uz = nuz; }
  }

  // ---- write partial state ----
  float* PSf = ws + WS_PS + b*PS_STRIDE;
  ushort_t* PSs = (ushort_t*)PSf;
  if (g < 2) {
#pragma unroll
    for (int i = 0; i < 4; ++i) {
      PSs[(4*g + i)*128 + ncol] = f2b(bh[i]);
      PSs[1024 + (4*g + i)*128 + ncol] = f2b(sna[i]);
    }
  }
  avx += __shfl_xor(avx, 1); avy += __shfl_xor(avy, 1); avz += __shfl_xor(avz, 1);
  avx += __shfl_xor(avx, 2); avy += __shfl_xor(avy, 2); avz += __shfl_xor(avz, 2);
  avx += __shfl_xor(avx, 4); avy += __shfl_xor(avy, 4); avz += __shfl_xor(avz, 4);
  avx += __shfl_xor(avx, 8); avy += __shfl_xor(avy, 8); avz += __shfl_xor(avz, 8);
  avx += __shfl_xor(avx,16); avy += __shfl_xor(avy,16); avz += __shfl_xor(avz,16);
  avx += __shfl_xor(avx,32); avy += __shfl_xor(avy,32); avz += __shfl_xor(avz,32);
  if (l == 0) {
    PSf[1024 + nw*3 + 0] = avx;
    PSf[1024 + nw*3 + 1] = avy;
    PSf[1024 + nw*3 + 2] = avz;
    PSf[1048 + nw] = mrun;
    PSf[1056 + nw] = drun;
  }
}

__global__ __launch_bounds__(128) void k_merge(
    const float* __restrict__ pos, const float* __restrict__ feat,
    const float* __restrict__ Wev,
    const float* __restrict__ Wo0, const float* __restrict__ bo0,
    const float* __restrict__ Wo1, const float* __restrict__ bo1,
    const float* __restrict__ Wo2, const float* __restrict__ bo2,
    const float* __restrict__ ws, float* __restrict__ out)
{
  const int r = blockIdx.x, j = threadIdx.x;
  __shared__ float S1s[8], S2s[8], Dh[8];
  __shared__ float BhC[1024];
  __shared__ float asB[128], o1[128], o2[128];
  const float* P1f = ws + WS_PS + (2*r)*PS_STRIDE;
  const float* P2f = P1f + PS_STRIDE;
  const ushort_t* P1s = (const ushort_t*)P1f;
  const ushort_t* P2s = (const ushort_t*)P2f;
  if (j < 8) {
    const float m1 = P1f[1048 + j], m2 = P2f[1048 + j];
    const float M = fmaxf(m1, m2);
    const float s1 = __expf(m1 - M), s2 = __expf(m2 - M);
    S1s[j] = s1; S2s[j] = s2;
    Dh[j] = s1*P1f[1056 + j] + s2*P2f[1056 + j];
  }
  __syncthreads();
#pragma unroll
  for (int h = 0; h < 8; ++h)
    BhC[h*128 + j] = S1s[h]*b2f(P1s[h*128 + j]) + S2s[h]*b2f(P2s[h*128 + j]);
  const int hh = j >> 4;
  const float snj = S1s[hh]*b2f(P1s[1024 + hh*128 + j])
                  + S2s[hh]*b2f(P2s[1024 + hh*128 + j]);
  if (j < 24) {
    const int v = j / 3;
    const float avc = S1s[v]*P1f[1024 + j] + S2s[v]*P2f[1024 + j];
    out[r*24 + j] = pos[r*24 + j]
        + 1.7320508076f * avc * __builtin_amdgcn_rcpf(Dh[v]);
  }
  __syncthreads();
  {
    float ev = 0.f;
#pragma unroll 4
    for (int m = 0; m < 128; ++m)
      ev = fmaf(BhC[hh*128 + m], Wev[m*128 + j], ev);
    asB[j] = (snj + ev) * __builtin_amdgcn_rcpf(Dh[hh]);
  }
  __syncthreads();
  {
    float acc = bo0[j];
#pragma unroll 4
    for (int i = 0; i < 128; ++i) acc = fmaf(asB[i], Wo0[i*128 + j], acc);
    o1[j] = fsilu(acc);
  }
  __syncthreads();
  {
    float acc = bo1[j];
#pragma unroll 4
    for (int i = 0; i < 128; ++i) acc = fmaf(o1[i], Wo1[i*128 + j], acc);
    o2[j] = fsilu(acc);
  }
  __syncthreads();
  {
    float acc = bo2[j];
#pragma unroll 4
    for (int i = 0; i < 128; ++i) acc = fmaf(o2[i], Wo2[i*128 + j], acc);
    out[12288 + r*128 + j] = feat[r*128 + j] + acc;
  }
}

extern "C" void kernel_launch(void* const* d_in, const int* in_sizes, int n_in,
                              void* d_out, int out_size, void* d_ws, size_t ws_size,
                              hipStream_t stream)
{
  const float* pos  = (const float*)d_in[0];
  const float* feat = (const float*)d_in[1];
  const float* We0  = (const float*)d_in[2];
  const float* be0  = (const float*)d_in[3];
  const float* We1  = (const float*)d_in[4];
  const float* be1  = (const float*)d_in[5];
  const float* Wq   = (const float*)d_in[6];
  const float* Wk   = (const float*)d_in[7];
  const float* Wek  = (const float*)d_in[8];
  const float* Wv   = (const float*)d_in[9];
  const float* Wev  = (const float*)d_in[10];
  const float* Wg   = (const float*)d_in[11];
  const float* Wo0  = (const float*)d_in[12];
  const float* bo0  = (const float*)d_in[13];
  const float* Wo1  = (const float*)d_in[14];
  const float* bo1  = (const float*)d_in[15];
  const float* Wo2  = (const float*)d_in[16];
  const float* bo2  = (const float*)d_in[17];
  float* ws  = (float*)d_ws;
  float* out = (float*)d_out;

  hipLaunchKernelGGL(k_nodeprep, dim3(512), dim3(128), 0, stream,
                     feat, Wq, Wk, Wv, Wek, Wg, ws);
  hipLaunchKernelGGL(k_lbase, dim3(512), dim3(512), 0, stream, ws);
  hipLaunchKernelGGL(k_wprep, dim3(96), dim3(256), 0, stream, We0, We1, ws);
  hipLaunchKernelGGL(k_edge7, dim3(1024), dim3(512), 0, stream,
                     pos, be0, be1, ws);
  hipLaunchKernelGGL(k_merge, dim3(512), dim3(128), 0, stream,
                     pos, feat, Wev, Wo0, bo0, Wo1, bo1, Wo2, bo2, ws, out);
}

// Round 8
// 127.320 us; speedup vs baseline: 1.9602x; 1.5343x over previous
//
#include <hip/hip_runtime.h>
#include <hip/hip_bf16.h>

// EnTransformerBlock, MFMA v8: v7 structure with launch_bounds spill fix
// (no waves-per-EU hint on k_edge -> compiler allocates real VGPR need).
// N=512, V=8, F=128, H=8, FH=16, B=8. Dense all-pairs edges.
//
// ws layout (float offsets):
//   kn   @ 0        f32 [512][128]
//   qn   @ 65536    f32 [512][128]
//   LbB  @ 131072   bf16[512][512][8]   (q.k per head, /4)        -> 1179648
//   vnT  @ 1179648  bf16[128][512]      (feat@Wv transposed)      -> 1212416
//   A4T  @ 1212416  bf16[512][8][128]   (Wek folded with q, /4)   -> 1474560
//   WgT  @ 1474560  bf16[8][128]        (Wg transposed)           -> 1475072
//   W0T  @ 1475072  bf16[128][64]       (We0 transposed)          -> 1479168
//   W1T  @ 1479168  bf16[128][128]      (We1 transposed)          -> 1487360
//   PS   @ 1487360  [1024][1072]

#define WS_KN   0
#define WS_QN   65536
#define WS_LBB  131072
#define WS_VNT  1179648
#define WS_A4T  1212416
#define WS_WGT  1474560
#define WS_W0T  1475072
#define WS_W1T  1479168
#define WS_PS   1487360
#define PS_STRIDE 1072

typedef short bf16x8 __attribute__((ext_vector_type(8)));
typedef short short4v __attribute__((ext_vector_type(4)));
typedef float f32x4 __attribute__((ext_vector_type(4)));
typedef unsigned short ushort_t;

static __device__ __forceinline__ ushort_t f2b(float x) {
  __hip_bfloat16 h = __float2bfloat16(x);
  return reinterpret_cast<ushort_t&>(h);
}
static __device__ __forceinline__ float b2f(ushort_t u) {
  unsigned v = ((unsigned)u) << 16;
  return reinterpret_cast<float&>(v);
}
static __device__ __forceinline__ float fsilu(float x) {
  return x * __builtin_amdgcn_rcpf(1.f + __expf(-x));
}

static __device__ __forceinline__ bf16x8 radial_frag(
    float dx, float dy, float dz, float& ux, float& uy, float& uz)
{
  const float l2 = fmaf(dx,dx, fmaf(dy,dy, fmaf(dz,dz, 1e-20f)));
  const float inv = rsqrtf(l2);
  const float len = l2 * inv;
  ux = dx*inv; uy = dy*inv; uz = dz*inv;
  const float yy = 2.f - len*0.2f;
  const float env = (yy > 0.f) ? 1.9784655648f * __expf(-__builtin_amdgcn_rcpf(yy)) : 0.f;
  const float coef = 0.4472135955f * env * inv;
  const float arg = len * 0.31415926535f;
  const float s1v = __sinf(arg), c1v = __cosf(arg);
  const float twc = 2.f*c1v;
  float sp = 0.f, sc = s1v;
  bf16x8 ev;
#pragma unroll
  for (int bb = 0; bb < 8; ++bb) {
    ev[bb] = (short)f2b(coef*sc);
    const float nx = fmaf(twc, sc, -sp);
    sp = sc; sc = nx;
  }
  return ev;
}

// blocks 0..511: per-node prep; blocks 512..703: weight transpose
__global__ __launch_bounds__(128) void k_prep(
    const float* __restrict__ feat, const float* __restrict__ Wq,
    const float* __restrict__ Wk, const float* __restrict__ Wv,
    const float* __restrict__ Wek, const float* __restrict__ Wg,
    const float* __restrict__ We0, const float* __restrict__ We1,
    float* __restrict__ ws)
{
  const int blk = blockIdx.x, j = threadIdx.x;
  if (blk >= 512) {
    const int i = (blk - 512)*128 + j;
    ushort_t* W0T = (ushort_t*)(ws + WS_W0T);
    ushort_t* W1T = (ushort_t*)(ws + WS_W1T);
    if (i < 8192) {
      const int n = i >> 6, k = i & 63;
      W0T[n*64 + k] = f2b(We0[k*128 + n]);
    } else {
      const int t = i - 8192, n = t >> 7, k = t & 127;
      W1T[n*128 + k] = f2b(We1[k*128 + n]);
    }
    return;
  }
  const int r = blk;
  __shared__ float fr[128];
  __shared__ float qL[128];
  fr[j] = feat[r*128 + j];
  __syncthreads();
  float aq = 0.f, ak = 0.f, av = 0.f;
#pragma unroll 4
  for (int i = 0; i < 128; ++i) {
    const float f = fr[i];
    aq = fmaf(f, Wq[i*128 + j], aq);
    ak = fmaf(f, Wk[i*128 + j], ak);
    av = fmaf(f, Wv[i*128 + j], av);
  }
  ws[WS_QN + r*128 + j] = aq;
  ws[WS_KN + r*128 + j] = ak;
  ushort_t* vnT = (ushort_t*)(ws + WS_VNT);
  vnT[j*512 + r] = f2b(av);
  qL[j] = aq;
  __syncthreads();
  ushort_t* A4 = (ushort_t*)(ws + WS_A4T) + r*1024;
  const float* wr = Wek + j*128;
#pragma unroll
  for (int h = 0; h < 8; ++h) {
    float acc = 0.f;
#pragma unroll
    for (int f = 0; f < 16; ++f)
      acc = fmaf(wr[16*h + f], qL[16*h + f], acc);
    A4[h*128 + j] = f2b(acc * 0.25f);
  }
  if (r == 0) {
    ushort_t* WgT = (ushort_t*)(ws + WS_WGT);
#pragma unroll
    for (int v = 0; v < 8; ++v)
      WgT[v*128 + j] = f2b(Wg[j*8 + v]);
  }
}

__global__ __launch_bounds__(512) void k_lbase(float* __restrict__ ws)
{
  const int r = blockIdx.x, s = threadIdx.x;
  __shared__ float qL[128];
  if (s < 128) qL[s] = ws[WS_QN + r*128 + s];
  __syncthreads();
  const float* knr = ws + WS_KN + s*128;
  ushort_t* Lb = (ushort_t*)(ws + WS_LBB) + (r*512 + s)*8;
#pragma unroll
  for (int h = 0; h < 8; ++h) {
    float acc = 0.f;
#pragma unroll
    for (int f = 0; f < 16; ++f)
      acc = fmaf(knr[16*h + f], qL[16*h + f], acc);
    Lb[h] = f2b(acc * 0.25f);
  }
}

// LDS (bytes): Es@0 [64][64]bf16 8192 | H1/H2r@8192 [64][128]bf16 16384 |
//   H2t@24576 [128][64]bf16 16384 | lgT@40960 f32[16][65] 4160 |
//   Pb@45120 bf16[16][64] 2048 | rscL@47168 f32[8] 32   (total 47200)
#define MFMA(a,b,c) __builtin_amdgcn_mfma_f32_16x16x32_bf16((a),(b),(c),0,0,0)

__global__ __launch_bounds__(512) void k_edge8(
    const float* __restrict__ pos,
    const float* __restrict__ be0, const float* __restrict__ be1,
    float* __restrict__ ws)
{
  __shared__ __align__(16) char Lds[47232];
  ushort_t* Es  = (ushort_t*)(Lds);
  ushort_t* H1  = (ushort_t*)(Lds + 8192);
  ushort_t* H2t = (ushort_t*)(Lds + 24576);
  float*    lgT = (float*)(Lds + 40960);
  ushort_t* Pb  = (ushort_t*)(Lds + 45120);
  float*    rscL= (float*)(Lds + 47168);

  const int tid = threadIdx.x;
  const int nw = tid >> 6, l = tid & 63;
  const int c = l & 15, g = l >> 4;
  const int b = blockIdx.x;
  const int r = b >> 1, half = b & 1;
  const int base = half * 256;

  const ushort_t* vnT = (const ushort_t*)(ws + WS_VNT);
  const ushort_t* A4G = (const ushort_t*)(ws + WS_A4T) + r*1024;
  const ushort_t* WgG = (const ushort_t*)(ws + WS_WGT);
  const ushort_t* W0T = (const ushort_t*)(ws + WS_W0T);
  const ushort_t* W1T = (const ushort_t*)(ws + WS_W1T);
  const ushort_t* LbG = (const ushort_t*)(ws + WS_LBB) + r*4096;

  const int ncol = nw*16 + c;
  const float be0v = be0[ncol], be1v = be1[ncol];
  const bf16x8 w0f0 = *(const bf16x8*)(W0T + ncol*64 + g*8);
  const bf16x8 w0f1 = *(const bf16x8*)(W0T + ncol*64 + 32 + g*8);

  // geometry identity: wave nw <-> vector v=nw, lane l <-> sender slot l
  const float prx = pos[r*24 + nw*3 + 0];
  const float pry = pos[r*24 + nw*3 + 1];
  const float prz = pos[r*24 + nw*3 + 2];

  f32x4 bh = {0,0,0,0}, sna = {0,0,0,0};
  float avx = 0.f, avy = 0.f, avz = 0.f;
  float mrun = -1e30f, drun = 0.f;
  float ux, uy, uz;

  // prologue: geometry tile 0
  {
    const int sg = base + l;
    const bf16x8 ev = radial_frag(pos[sg*24 + nw*3 + 0] - prx,
                                  pos[sg*24 + nw*3 + 1] - pry,
                                  pos[sg*24 + nw*3 + 2] - prz, ux, uy, uz);
    *(bf16x8*)(Es + l*64 + ((nw ^ (l&7))<<3)) = ev;
  }
  __syncthreads();

  for (int tile = 0; tile < 4; ++tile) {
    const int gbase = base + tile*64;

    // early global prefetches (consumed stages later)
    float npx = 0.f, npy = 0.f, npz = 0.f;
    if (tile < 3) {
      const int sg = gbase + 64 + l;
      npx = pos[sg*24 + nw*3 + 0];
      npy = pos[sg*24 + nw*3 + 1];
      npz = pos[sg*24 + nw*3 + 2];
    }
    const ushort_t lbp = LbG[(gbase + l)*8 + nw];

    // ---- s0: L0 (Es @ We0 -> H1) ----
#pragma unroll
    for (int m = 0; m < 4; ++m) {
      const int ra = m*16 + c;
      const bf16x8 e0 = *(const bf16x8*)(Es + ra*64 + (((g  ) ^ (ra&7))<<3));
      const bf16x8 e1 = *(const bf16x8*)(Es + ra*64 + (((4+g) ^ (ra&7))<<3));
      f32x4 acc = {0,0,0,0};
      acc = MFMA(e0, w0f0, acc);
      acc = MFMA(e1, w0f1, acc);
#pragma unroll
      for (int i = 0; i < 4; ++i) {
        const int row = m*16 + g*4 + i;
        H1[row*128 + (((ncol>>3) ^ (row&15))<<3) + (c&7)] =
            f2b(fsilu(acc[i] + be0v));
      }
    }
    __syncthreads();  // B: H1 ready

    // ---- s1a: L1 accumulate (reads H1) + geometry(t+1) ----
    f32x4 a1[4];
#pragma unroll
    for (int m = 0; m < 4; ++m) {
      const int ra = m*16 + c;
      f32x4 acc = {0,0,0,0};
#pragma unroll
      for (int kb = 0; kb < 4; ++kb) {
        const bf16x8 af = *(const bf16x8*)(H1 + ra*128 + (((kb*4+g) ^ (ra&15))<<3));
        const bf16x8 wf = *(const bf16x8*)(W1T + ncol*128 + kb*32 + g*8);
        acc = MFMA(af, wf, acc);
      }
      a1[m] = acc;
    }
    float nux = 0.f, nuy = 0.f, nuz = 0.f;
    if (tile < 3) {
      const bf16x8 ev = radial_frag(npx - prx, npy - pry, npz - prz, nux, nuy, nuz);
      *(bf16x8*)(Es + l*64 + ((nw ^ (l&7))<<3)) = ev;
    }
    __syncthreads();  // C1: H1 fully consumed; Es(t+1) staged

    // ---- s1b: silu -> H2r (aliases H1) + H2t ----
#pragma unroll
    for (int m = 0; m < 4; ++m) {
      short4v pk;
#pragma unroll
      for (int i = 0; i < 4; ++i) {
        const int row = m*16 + g*4 + i;
        const ushort_t bv = f2b(fsilu(a1[m][i] + be1v));
        H1[row*128 + (((ncol>>3) ^ (row&15))<<3) + (c&7)] = bv;
        pk[i] = (short)bv;
      }
      *(short4v*)(H2t + ncol*64 + (((m*2 + (g>>1)) ^ (ncol&7))<<3) + ((g&1)<<2)) = pk;
    }
    __syncthreads();  // C2: H2r/H2t ready

    // ---- s2: LG (waves 0-3): lg[sender][ch] -> lgT[ch][sender] ----
    if (nw < 4) {
      const int ra = nw*16 + c;
      const ushort_t* ab = (c < 8) ? (A4G + c*128) : (WgG + (c-8)*128);
      f32x4 lg = {0,0,0,0};
#pragma unroll
      for (int kb = 0; kb < 4; ++kb) {
        const bf16x8 af = *(const bf16x8*)(H1 + ra*128 + (((kb*4+g) ^ (ra&15))<<3));
        const bf16x8 aw = *(const bf16x8*)(ab + kb*32 + g*8);
        lg = MFMA(af, aw, lg);
      }
#pragma unroll
      for (int i = 0; i < 4; ++i)
        lgT[c*65 + nw*16 + g*4 + i] = lg[i];
    }
    __syncthreads();  // S1: lgT ready

    // ---- s3: softmax (wave = head h = nw) + equivariant VALU accum ----
    const bf16x8 vnf0 = *(const bf16x8*)(vnT + ncol*512 + gbase + g*8);
    const bf16x8 vnf1 = *(const bf16x8*)(vnT + ncol*512 + gbase + 32 + g*8);
    {
      const int h = nw;
      float lgv = lgT[h*65 + l] + b2f(lbp);
      const float gate = lgT[(8+h)*65 + l];
      if (gbase + l == r) lgv = -1e30f;
      float t = lgv;
      t = fmaxf(t, __shfl_xor(t, 1));
      t = fmaxf(t, __shfl_xor(t, 2));
      t = fmaxf(t, __shfl_xor(t, 4));
      t = fmaxf(t, __shfl_xor(t, 8));
      t = fmaxf(t, __shfl_xor(t, 16));
      t = fmaxf(t, __shfl_xor(t, 32));
      const float mnew = fmaxf(mrun, t);
      const float rsc = __expf(mrun - mnew);
      mrun = mnew;
      const float val = __expf(lgv - mnew);
      float wsm = val;
      wsm += __shfl_xor(wsm, 1);
      wsm += __shfl_xor(wsm, 2);
      wsm += __shfl_xor(wsm, 4);
      wsm += __shfl_xor(wsm, 8);
      wsm += __shfl_xor(wsm, 16);
      wsm += __shfl_xor(wsm, 32);
      drun = drun*rsc + wsm;
      const float ga = val * gate;
      Pb[h*64 + (((l>>3) ^ h)<<3) + (l&7)] = f2b(val);
      Pb[(8+h)*64 + (((l>>3) ^ h)<<3) + (l&7)] = f2b(ga);
      if (l == 0) rscL[h] = rsc;
      avx = avx*rsc + ga*ux;
      avy = avy*rsc + ga*uy;
      avz = avz*rsc + ga*uz;
    }
    __syncthreads();  // S2: Pb/rscL ready

    // ---- s4: rescale + P-MFMAs ----
    {
      float rs[4];
#pragma unroll
      for (int i = 0; i < 4; ++i) rs[i] = rscL[(4*g + i) & 7];
#pragma unroll
      for (int i = 0; i < 4; ++i) { bh[i] *= rs[i]; sna[i] *= rs[i]; }
      const bf16x8 pa0 = *(const bf16x8*)(Pb + c*64 + (((g  ) ^ (c&7))<<3));
      const bf16x8 pa1 = *(const bf16x8*)(Pb + c*64 + (((4+g) ^ (c&7))<<3));
      bh = MFMA(pa0, *(const bf16x8*)(H2t + ncol*64 + (((g  ) ^ (ncol&7))<<3)), bh);
      bh = MFMA(pa1, *(const bf16x8*)(H2t + ncol*64 + (((4+g) ^ (ncol&7))<<3)), bh);
      sna = MFMA(pa0, vnf0, sna);
      sna = MFMA(pa1, vnf1, sna);
    }
    if (tile < 3) { ux = nux; uy = nuy; uz = nuz; }
  }

  // ---- write partial state ----
  float* PSf = ws + WS_PS + b*PS_STRIDE;
  ushort_t* PSs = (ushort_t*)PSf;
  if (g < 2) {
#pragma unroll
    for (int i = 0; i < 4; ++i) {
      PSs[(4*g + i)*128 + ncol] = f2b(bh[i]);
      PSs[1024 + (4*g + i)*128 + ncol] = f2b(sna[i]);
    }
  }
  avx += __shfl_xor(avx, 1); avy += __shfl_xor(avy, 1); avz += __shfl_xor(avz, 1);
  avx += __shfl_xor(avx, 2); avy += __shfl_xor(avy, 2); avz += __shfl_xor(avz, 2);
  avx += __shfl_xor(avx, 4); avy += __shfl_xor(avy, 4); avz += __shfl_xor(avz, 4);
  avx += __shfl_xor(avx, 8); avy += __shfl_xor(avy, 8); avz += __shfl_xor(avz, 8);
  avx += __shfl_xor(avx,16); avy += __shfl_xor(avy,16); avz += __shfl_xor(avz,16);
  avx += __shfl_xor(avx,32); avy += __shfl_xor(avy,32); avz += __shfl_xor(avz,32);
  if (l == 0) {
    PSf[1024 + nw*3 + 0] = avx;
    PSf[1024 + nw*3 + 1] = avy;
    PSf[1024 + nw*3 + 2] = avz;
    PSf[1048 + nw] = mrun;
    PSf[1056 + nw] = drun;
  }
}

__global__ __launch_bounds__(128) void k_merge(
    const float* __restrict__ pos, const float* __restrict__ feat,
    const float* __restrict__ Wev,
    const float* __restrict__ Wo0, const float* __restrict__ bo0,
    const float* __restrict__ Wo1, const float* __restrict__ bo1,
    const float* __restrict__ Wo2, const float* __restrict__ bo2,
    const float* __restrict__ ws, float* __restrict__ out)
{
  const int r = blockIdx.x, j = threadIdx.x;
  __shared__ float S1s[8], S2s[8], Dh[8];
  __shared__ float BhC[1024];
  __shared__ float asB[128], o1[128], o2[128];
  const float* P1f = ws + WS_PS + (2*r)*PS_STRIDE;
  const float* P2f = P1f + PS_STRIDE;
  const ushort_t* P1s = (const ushort_t*)P1f;
  const ushort_t* P2s = (const ushort_t*)P2f;
  if (j < 8) {
    const float m1 = P1f[1048 + j], m2 = P2f[1048 + j];
    const float M = fmaxf(m1, m2);
    const float s1 = __expf(m1 - M), s2 = __expf(m2 - M);
    S1s[j] = s1; S2s[j] = s2;
    Dh[j] = s1*P1f[1056 + j] + s2*P2f[1056 + j];
  }
  __syncthreads();
#pragma unroll
  for (int h = 0; h < 8; ++h)
    BhC[h*128 + j] = S1s[h]*b2f(P1s[h*128 + j]) + S2s[h]*b2f(P2s[h*128 + j]);
  const int hh = j >> 4;
  const float snj = S1s[hh]*b2f(P1s[1024 + hh*128 + j])
                  + S2s[hh]*b2f(P2s[1024 + hh*128 + j]);
  if (j < 24) {
    const int v = j / 3;
    const float avc = S1s[v]*P1f[1024 + j] + S2s[v]*P2f[1024 + j];
    out[r*24 + j] = pos[r*24 + j]
        + 1.7320508076f * avc * __builtin_amdgcn_rcpf(Dh[v]);
  }
  __syncthreads();
  {
    float ev = 0.f;
#pragma unroll 4
    for (int m = 0; m < 128; ++m)
      ev = fmaf(BhC[hh*128 + m], Wev[m*128 + j], ev);
    asB[j] = (snj + ev) * __builtin_amdgcn_rcpf(Dh[hh]);
  }
  __syncthreads();
  {
    float acc = bo0[j];
#pragma unroll 4
    for (int i = 0; i < 128; ++i) acc = fmaf(asB[i], Wo0[i*128 + j], acc);
    o1[j] = fsilu(acc);
  }
  __syncthreads();
  {
    float acc = bo1[j];
#pragma unroll 4
    for (int i = 0; i < 128; ++i) acc = fmaf(o1[i], Wo1[i*128 + j], acc);
    o2[j] = fsilu(acc);
  }
  __syncthreads();
  {
    float acc = bo2[j];
#pragma unroll 4
    for (int i = 0; i < 128; ++i) acc = fmaf(o2[i], Wo2[i*128 + j], acc);
    out[12288 + r*128 + j] = feat[r*128 + j] + acc;
  }
}

extern "C" void kernel_launch(void* const* d_in, const int* in_sizes, int n_in,
                              void* d_out, int out_size, void* d_ws, size_t ws_size,
                              hipStream_t stream)
{
  const float* pos  = (const float*)d_in[0];
  const float* feat = (const float*)d_in[1];
  const float* We0  = (const float*)d_in[2];
  const float* be0  = (const float*)d_in[3];
  const float* We1  = (const float*)d_in[4];
  const float* be1  = (const float*)d_in[5];
  const float* Wq   = (const float*)d_in[6];
  const float* Wk   = (const float*)d_in[7];
  const float* Wek  = (const float*)d_in[8];
  const float* Wv   = (const float*)d_in[9];
  const float* Wev  = (const float*)d_in[10];
  const float* Wg   = (const float*)d_in[11];
  const float* Wo0  = (const float*)d_in[12];
  const float* bo0  = (const float*)d_in[13];
  const float* Wo1  = (const float*)d_in[14];
  const float* bo1  = (const float*)d_in[15];
  const float* Wo2  = (const float*)d_in[16];
  const float* bo2  = (const float*)d_in[17];
  float* ws  = (float*)d_ws;
  float* out = (float*)d_out;

  hipLaunchKernelGGL(k_prep, dim3(704), dim3(128), 0, stream,
                     feat, Wq, Wk, Wv, Wek, Wg, We0, We1, ws);
  hipLaunchKernelGGL(k_lbase, dim3(512), dim3(512), 0, stream, ws);
  hipLaunchKernelGGL(k_edge8, dim3(1024), dim3(512), 0, stream,
                     pos, be0, be1, ws);
  hipLaunchKernelGGL(k_merge, dim3(512), dim3(128), 0, stream,
                     pos, feat, Wev, Wo0, bo0, Wo1, bo1, Wo2, bo2, ws, out);
}